// Round 1
// baseline (602.619 us; speedup 1.0000x reference)
//
#include <hip/hip_runtime.h>

static constexpr int BATCH = 128;
static constexpr int LEN   = 131072;
static constexpr int T     = 4096;   // LEN / 32
static constexpr int DIM   = 32;
static constexpr int NP    = 16;

#define L2E   1.44269504088896340736f
#define L2E16 (1.44269504088896340736f / 16.0f)

__device__ __forceinline__ float fexp2(float x) {
#if __has_builtin(__builtin_amdgcn_exp2f)
  return __builtin_amdgcn_exp2f(x);
#else
  return exp2f(x);
#endif
}

__device__ __forceinline__ float frcp(float x) {
#if __has_builtin(__builtin_amdgcn_rcpf)
  return __builtin_amdgcn_rcpf(x);
#else
  return 1.0f / x;
#endif
}

template <int CTRL>
__device__ __forceinline__ float dppf(float v) {
  return __int_as_float(
      __builtin_amdgcn_update_dpp(0, __float_as_int(v), CTRL, 0xf, 0xf, true));
}

// Sum across each 16-lane group (p dimension). Butterfly over xor masks
// {1, 2, 7, 15} (a basis of (Z2)^4): quad_perm[1,0,3,2]=0xB1, quad_perm
// [2,3,0,1]=0x4E, row_half_mirror=0x141, row_mirror=0x140. All DPP = VALU pipe.
__device__ __forceinline__ float sum16(float v) {
  v += dppf<0xB1>(v);
  v += dppf<0x4E>(v);
  v += dppf<0x141>(v);
  v += dppf<0x140>(v);
  return v;
}

// Stage 1: one thread per (b, t). Computes conv1d(K=64,stride=32)+bias+ReLU
// over 32 dims, then scores = clip(out·keys, 0, 6) * log2(e), stored [t][b][p].
__global__ void __launch_bounds__(256) scores_kernel(
    const float* __restrict__ x, const float* __restrict__ conv_w,
    const float* __restrict__ conv_b, const float* __restrict__ keys,
    float* __restrict__ scoresL) {
  int gid = blockIdx.x * 256 + threadIdx.x;   // gid = b*T + t (t fastest)
  int b = gid >> 12;
  int t = gid & (T - 1);
  const float* xb = x + (size_t)b * LEN;

  // Window of x for output t: x[32t-63 .. 32t]. Load aligned superset
  // x[32t-64 .. 32t+3] as 17 float4 (16B-aligned since 32t-64 % 4 == 0).
  float xr[68];
  int base = t * 32 - 64;
#pragma unroll
  for (int q = 0; q < 17; ++q) {
    int bi = base + 4 * q;
    float4 v;
    if (bi >= 0) v = *(const float4*)(xb + bi);   // whole quads are in/out (4-aligned)
    else         v = make_float4(0.f, 0.f, 0.f, 0.f);
    xr[4 * q + 0] = v.x; xr[4 * q + 1] = v.y;
    xr[4 * q + 2] = v.z; xr[4 * q + 3] = v.w;
  }

  float acc[DIM];
#pragma unroll
  for (int d = 0; d < DIM; ++d) acc[d] = conv_b[d];  // uniform -> SMEM load
#pragma unroll
  for (int d = 0; d < DIM; ++d) {
#pragma unroll
    for (int h = 0; h < 64; ++h)
      acc[d] = fmaf(xr[h + 1], conv_w[d * 64 + h], acc[d]);  // w uniform -> SGPR
  }

  float sc[NP];
#pragma unroll
  for (int p = 0; p < NP; ++p) sc[p] = 0.f;
#pragma unroll
  for (int d = 0; d < DIM; ++d) {
    float od = fmaxf(acc[d], 0.f);
#pragma unroll
    for (int p = 0; p < NP; ++p) sc[p] = fmaf(od, keys[d * NP + p], sc[p]);
  }

  float* dst = scoresL + ((size_t)t * BATCH + b) * NP;
#pragma unroll
  for (int p = 0; p < NP; ++p)
    sc[p] = fminf(fmaxf(sc[p], 0.f), 6.f) * L2E;   // clip, pre-scale for exp2
#pragma unroll
  for (int q = 0; q < 4; ++q)
    *(float4*)(dst + 4 * q) =
        make_float4(sc[4 * q], sc[4 * q + 1], sc[4 * q + 2], sc[4 * q + 3]);
}

// Stage 2: sequential softmax-scan. 32 blocks x 64 threads; each wave owns 4
// batches (16 lanes per batch = one pattern per lane). A = avg * log2e so the
// critical chain is: sub -> v_exp_f32 -> 4x dpp-add -> v_rcp -> mul -> fma.
// No max-subtraction needed: scores in [0,6], sum(avg)=0 invariant keeps exp
// args bounded, and max(s) >= mean(s) >= 0 so the denominator >= 1.
__global__ void __launch_bounds__(64) scan_kernel(
    const float* __restrict__ scoresL, const float* __restrict__ avg0,
    const float* __restrict__ shapes, float2* __restrict__ osd) {
  constexpr int BP = BATCH * NP;  // 2048
  int lane = threadIdx.x;
  int gid = blockIdx.x * 64 + lane;   // = b*16 + p
  int p = lane & 15;
  int bb = gid >> 4;
  float A = avg0[gid] * L2E;
  float sh0 = shapes[2 * p];
  float sh1 = shapes[2 * p + 1];
  const float* sp = scoresL + gid;

  constexpr int U = 16;  // prefetch ring: ~16 steps ahead (~800 cyc) hides HBM
  float buf[U];
#pragma unroll
  for (int i = 0; i < U; ++i) buf[i] = sp[(size_t)i * BP];

  for (int t0 = 0; t0 < T; t0 += U) {
    float nb[U];
    const bool more = (t0 + U) < T;
#pragma unroll
    for (int i = 0; i < U; ++i)
      nb[i] = more ? sp[(size_t)(t0 + U + i) * BP] : 0.f;
#pragma unroll
    for (int i = 0; i < U; ++i) {
      float s = buf[i] - A;           // (score - avg) * log2e
      float e = fexp2(s);
      float r = sum16(e);
      float prob = e * frcp(r);
      A = fmaf(prob, L2E, A - L2E16); // avg += prob - 1/16 (in log2e units)
      float o0 = sum16(prob * sh0);   // shapeparams, off the critical chain
      float o1 = sum16(prob * sh1);
      if (p == 0) osd[(size_t)bb * T + (t0 + i)] = make_float2(o0, o1);
    }
#pragma unroll
    for (int i = 0; i < U; ++i) buf[i] = nb[i];
  }
}

// Stage 3: memory-bound elementwise. out = relu(offset + noise*std - x).
__global__ void __launch_bounds__(256) out_kernel(
    const float* __restrict__ x, const float* __restrict__ noise,
    const float2* __restrict__ osd, float* __restrict__ out) {
  size_t gid = (size_t)blockIdx.x * 256 + threadIdx.x;
  size_t i4 = gid * 4;
  int b = (int)(i4 >> 17);          // / LEN
  int l = (int)(i4 & (LEN - 1));
  int t = l >> 5;                   // window index (4-aligned quad never spans t)
  float2 os = osd[(size_t)b * T + t];
  float4 xv = *(const float4*)(x + i4);
  float4 nv = *(const float4*)(noise + i4);
  float4 o;
  o.x = fmaxf(fmaf(nv.x, os.y, os.x) - xv.x, 0.f);
  o.y = fmaxf(fmaf(nv.y, os.y, os.x) - xv.y, 0.f);
  o.z = fmaxf(fmaf(nv.z, os.y, os.x) - xv.z, 0.f);
  o.w = fmaxf(fmaf(nv.w, os.y, os.x) - xv.w, 0.f);
  *(float4*)(out + i4) = o;
}

extern "C" void kernel_launch(void* const* d_in, const int* in_sizes, int n_in,
                              void* d_out, int out_size, void* d_ws, size_t ws_size,
                              hipStream_t stream) {
  const float* x      = (const float*)d_in[0];
  const float* avg0   = (const float*)d_in[1];
  const float* noise  = (const float*)d_in[2];
  const float* conv_w = (const float*)d_in[3];
  const float* conv_b = (const float*)d_in[4];
  const float* keys   = (const float*)d_in[5];
  const float* shapes = (const float*)d_in[6];
  float* out = (float*)d_out;

  float*  scoresL = (float*)d_ws;                               // 33.5 MB
  float2* osd = (float2*)((char*)d_ws + (size_t)T * BATCH * NP * 4);  // 4 MB

  scores_kernel<<<(BATCH * T) / 256, 256, 0, stream>>>(x, conv_w, conv_b, keys, scoresL);
  scan_kernel<<<(BATCH * NP) / 64, 64, 0, stream>>>(scoresL, avg0, shapes, osd);
  out_kernel<<<(int)((size_t)BATCH * LEN / 4 / 256), 256, 0, stream>>>(x, noise, osd, out);
}

// Round 2
// 567.178 us; speedup vs baseline: 1.0625x; 1.0625x over previous
//
#include <hip/hip_runtime.h>

static constexpr int BATCH = 128;
static constexpr int LEN   = 131072;
static constexpr int T     = 4096;   // LEN / 32
static constexpr int DIM   = 32;
static constexpr int NP    = 16;

#define L2E   1.44269504088896340736f
#define L2E16 (1.44269504088896340736f / 16.0f)

__device__ __forceinline__ float fexp2(float x) {
#if __has_builtin(__builtin_amdgcn_exp2f)
  return __builtin_amdgcn_exp2f(x);
#else
  return exp2f(x);
#endif
}

__device__ __forceinline__ float frcp(float x) {
#if __has_builtin(__builtin_amdgcn_rcpf)
  return __builtin_amdgcn_rcpf(x);
#else
  return 1.0f / x;
#endif
}

template <int CTRL>
__device__ __forceinline__ float dppf(float v) {
  return __int_as_float(
      __builtin_amdgcn_update_dpp(0, __float_as_int(v), CTRL, 0xf, 0xf, true));
}

// Sum across each 16-lane group (p dimension). Butterfly over xor masks
// {1, 2, 7, 15}: quad_perm[1,0,3,2]=0xB1, quad_perm[2,3,0,1]=0x4E,
// row_half_mirror=0x141, row_mirror=0x140. All DPP = VALU pipe, no LDS.
__device__ __forceinline__ float sum16(float v) {
  v += dppf<0xB1>(v);
  v += dppf<0x4E>(v);
  v += dppf<0x141>(v);
  v += dppf<0x140>(v);
  return v;
}

// Stage 1: one thread per (b, t). Computes conv1d(K=64,stride=32)+bias+ReLU
// over 32 dims, then scores = clip(out·keys, 0, 6) * log2(e).
// Output layout [g=gid>>6][t][lane=gid&63] (gid = b*16+p) so that the scan
// wave g reads CONTIGUOUS 256B lines as t advances (streaming, L2-friendly).
__global__ void __launch_bounds__(256) scores_kernel(
    const float* __restrict__ x, const float* __restrict__ conv_w,
    const float* __restrict__ conv_b, const float* __restrict__ keys,
    float* __restrict__ scores2) {
  int gid = blockIdx.x * 256 + threadIdx.x;   // gid = b*T + t (t fastest)
  int b = gid >> 12;
  int t = gid & (T - 1);
  const float* xb = x + (size_t)b * LEN;

  // Window of x for output t: x[32t-63 .. 32t]. Load aligned superset
  // x[32t-64 .. 32t+3] as 17 float4 (16B-aligned since 32t-64 % 4 == 0).
  float xr[68];
  int base = t * 32 - 64;
#pragma unroll
  for (int q = 0; q < 17; ++q) {
    int bi = base + 4 * q;
    float4 v;
    if (bi >= 0) v = *(const float4*)(xb + bi);   // whole quads are in/out
    else         v = make_float4(0.f, 0.f, 0.f, 0.f);
    xr[4 * q + 0] = v.x; xr[4 * q + 1] = v.y;
    xr[4 * q + 2] = v.z; xr[4 * q + 3] = v.w;
  }

  float acc[DIM];
#pragma unroll
  for (int d = 0; d < DIM; ++d) acc[d] = conv_b[d];  // uniform -> scalar load
#pragma unroll
  for (int d = 0; d < DIM; ++d) {
#pragma unroll
    for (int h = 0; h < 64; ++h)
      acc[d] = fmaf(xr[h + 1], conv_w[d * 64 + h], acc[d]);  // w uniform
  }

  float sc[NP];
#pragma unroll
  for (int p = 0; p < NP; ++p) sc[p] = 0.f;
#pragma unroll
  for (int d = 0; d < DIM; ++d) {
    float od = fmaxf(acc[d], 0.f);
#pragma unroll
    for (int p = 0; p < NP; ++p) sc[p] = fmaf(od, keys[d * NP + p], sc[p]);
  }

  // dest: scores2[(b>>2)][t][(b&3)*16 + p] — 64B contiguous per thread.
  float* dst = scores2 + ((size_t)(b >> 2) * T + t) * 64 + (b & 3) * 16;
#pragma unroll
  for (int p = 0; p < NP; ++p)
    sc[p] = fminf(fmaxf(sc[p], 0.f), 6.f) * L2E;   // clip, pre-scale for exp2
#pragma unroll
  for (int q = 0; q < 4; ++q)
    *(float4*)(dst + 4 * q) =
        make_float4(sc[4 * q], sc[4 * q + 1], sc[4 * q + 2], sc[4 * q + 3]);
}

// Stage 2: sequential softmax-scan. 32 blocks x 64 threads; each wave owns 4
// batches (16 lanes per batch = one pattern per lane). A = avg * log2e so the
// critical chain per step is: sub -> v_exp_f32 -> 4x(dpp+add) -> rcp -> fma.
// Register ring prefetches U=16 steps ahead; the asm memory fences pin the
// load issue before the compute block (R1: compiler sank loads -> VGPR=24 and
// exposed ~250cyc memory latency per step).
__global__ void __launch_bounds__(64) scan_kernel(
    const float* __restrict__ scores2, const float* __restrict__ avg0,
    const float* __restrict__ shapes, float2* __restrict__ osd) {
  int lane = threadIdx.x;
  int g = blockIdx.x;
  int gid = g * 64 + lane;    // = b*16 + p
  int p = lane & 15;
  int bb = gid >> 4;
  float A = avg0[gid] * L2E;
  float sh0 = shapes[2 * p];
  float sh1 = shapes[2 * p + 1];
  const float* sp = scores2 + (size_t)g * T * 64 + lane;

  constexpr int U = 16;  // prefetch ring: ~16 steps (~1000+ cyc) of cover
  float buf[U];
#pragma unroll
  for (int i = 0; i < U; ++i) buf[i] = sp[i * 64];
  asm volatile("" ::: "memory");   // pin prefetch issue before compute

  for (int t0 = 0; t0 < T; t0 += U) {
    float nb[U];
    if (t0 + U < T) {
#pragma unroll
      for (int i = 0; i < U; ++i) nb[i] = sp[(size_t)(t0 + U + i) * 64];
    } else {
#pragma unroll
      for (int i = 0; i < U; ++i) nb[i] = 0.f;
    }
    asm volatile("" ::: "memory");  // loads for chunk k+1 issue HERE,
                                    // before chunk k's compute below
#pragma unroll
    for (int i = 0; i < U; ++i) {
      float s = buf[i] - A;           // (score - avg) * log2e
      float e = fexp2(s);
      float r = sum16(e);             // 4x dpp+add, on the chain
      float eL = e * L2E;             // off-chain, parallel with sum16
      float Am = A - L2E16;           // off-chain
      float rc = frcp(r);
      A = fmaf(eL, rc, Am);           // avg += prob - 1/16 (log2e units)
      float prob = e * rc;
      float o0 = sum16(prob * sh0);   // shapeparams, off the critical chain
      float o1 = sum16(prob * sh1);
      if (p == 0) osd[(size_t)bb * T + (t0 + i)] = make_float2(o0, o1);
    }
#pragma unroll
    for (int i = 0; i < U; ++i) buf[i] = nb[i];
  }
}

// Stage 3: memory-bound elementwise. out = relu(offset + noise*std - x).
__global__ void __launch_bounds__(256) out_kernel(
    const float* __restrict__ x, const float* __restrict__ noise,
    const float2* __restrict__ osd, float* __restrict__ out) {
  size_t gid = (size_t)blockIdx.x * 256 + threadIdx.x;
  size_t i4 = gid * 4;
  int b = (int)(i4 >> 17);          // / LEN
  int l = (int)(i4 & (LEN - 1));
  int t = l >> 5;                   // window index (quad never spans t)
  float2 os = osd[(size_t)b * T + t];
  float4 xv = *(const float4*)(x + i4);
  float4 nv = *(const float4*)(noise + i4);
  float4 o;
  o.x = fmaxf(fmaf(nv.x, os.y, os.x) - xv.x, 0.f);
  o.y = fmaxf(fmaf(nv.y, os.y, os.x) - xv.y, 0.f);
  o.z = fmaxf(fmaf(nv.z, os.y, os.x) - xv.z, 0.f);
  o.w = fmaxf(fmaf(nv.w, os.y, os.x) - xv.w, 0.f);
  *(float4*)(out + i4) = o;
}

extern "C" void kernel_launch(void* const* d_in, const int* in_sizes, int n_in,
                              void* d_out, int out_size, void* d_ws, size_t ws_size,
                              hipStream_t stream) {
  const float* x      = (const float*)d_in[0];
  const float* avg0   = (const float*)d_in[1];
  const float* noise  = (const float*)d_in[2];
  const float* conv_w = (const float*)d_in[3];
  const float* conv_b = (const float*)d_in[4];
  const float* keys   = (const float*)d_in[5];
  const float* shapes = (const float*)d_in[6];
  float* out = (float*)d_out;

  float*  scores2 = (float*)d_ws;                                    // 33.5 MB
  float2* osd = (float2*)((char*)d_ws + (size_t)T * BATCH * NP * 4); // 4 MB

  scores_kernel<<<(BATCH * T) / 256, 256, 0, stream>>>(x, conv_w, conv_b, keys, scores2);
  scan_kernel<<<(BATCH * NP) / 64, 64, 0, stream>>>(scores2, avg0, shapes, osd);
  out_kernel<<<(int)((size_t)BATCH * LEN / 4 / 256), 256, 0, stream>>>(x, noise, osd, out);
}

// Round 3
// 161.614 us; speedup vs baseline: 3.7288x; 3.5095x over previous
//
#include <hip/hip_runtime.h>

static constexpr int BATCH = 128;
static constexpr int LEN   = 131072;
static constexpr int T     = 4096;   // LEN / 32
static constexpr int DIM   = 32;
static constexpr int NP    = 16;

static constexpr int NCHUNK = 64;         // speculative chunks over T
static constexpr int SPC    = T / NCHUNK; // 64 steps per chunk
static constexpr int WARM   = 192;        // warm-up steps (contraction 0.9375^192 ~ 4e-6)

#define L2E   1.44269504088896340736f
#define L2E16 (1.44269504088896340736f / 16.0f)

typedef _Float16 half2v __attribute__((ext_vector_type(2)));

__device__ __forceinline__ float fexp2(float x) {
#if __has_builtin(__builtin_amdgcn_exp2f)
  return __builtin_amdgcn_exp2f(x);
#else
  return exp2f(x);
#endif
}

__device__ __forceinline__ float frcp(float x) {
#if __has_builtin(__builtin_amdgcn_rcpf)
  return __builtin_amdgcn_rcpf(x);
#else
  return 1.0f / x;
#endif
}

template <int CTRL>
__device__ __forceinline__ float dppf(float v) {
  return __int_as_float(
      __builtin_amdgcn_update_dpp(0, __float_as_int(v), CTRL, 0xf, 0xf, true));
}

// Sum across each 16-lane group (p dimension). Butterfly over xor masks
// {1, 2, 7, 15}: quad_perm[1,0,3,2]=0xB1, quad_perm[2,3,0,1]=0x4E,
// row_half_mirror=0x141, row_mirror=0x140. All DPP = VALU pipe, no LDS.
__device__ __forceinline__ float sum16(float v) {
  v += dppf<0xB1>(v);
  v += dppf<0x4E>(v);
  v += dppf<0x141>(v);
  v += dppf<0x140>(v);
  return v;
}

// Stage 1: one thread per (b, t). conv1d(K=64,stride=32)+bias+ReLU over 32
// dims, then scores = clip(out·keys,0,6)*log2e, stored f16 (16.7MB -> fits
// aggregate L2; quantization ~0.004 absolute, far under threshold).
// Layout [g=b>>2][t][(b&3)*16+p]: scan wave g streams contiguous 128B lines.
__global__ void __launch_bounds__(256) scores_kernel(
    const float* __restrict__ x, const float* __restrict__ conv_w,
    const float* __restrict__ conv_b, const float* __restrict__ keys,
    _Float16* __restrict__ scoresh) {
  int gid = blockIdx.x * 256 + threadIdx.x;   // gid = b*T + t (t fastest)
  int b = gid >> 12;
  int t = gid & (T - 1);
  const float* xb = x + (size_t)b * LEN;

  // Window for output t: x[32t-63 .. 32t]; load aligned superset as 17 float4.
  float xr[68];
  int base = t * 32 - 64;
#pragma unroll
  for (int q = 0; q < 17; ++q) {
    int bi = base + 4 * q;
    float4 v;
    if (bi >= 0) v = *(const float4*)(xb + bi);
    else         v = make_float4(0.f, 0.f, 0.f, 0.f);
    xr[4 * q + 0] = v.x; xr[4 * q + 1] = v.y;
    xr[4 * q + 2] = v.z; xr[4 * q + 3] = v.w;
  }

  float acc[DIM];
#pragma unroll
  for (int d = 0; d < DIM; ++d) acc[d] = conv_b[d];  // uniform -> scalar load
#pragma unroll
  for (int d = 0; d < DIM; ++d) {
#pragma unroll
    for (int h = 0; h < 64; ++h)
      acc[d] = fmaf(xr[h + 1], conv_w[d * 64 + h], acc[d]);  // w uniform
  }

  float sc[NP];
#pragma unroll
  for (int p = 0; p < NP; ++p) sc[p] = 0.f;
#pragma unroll
  for (int d = 0; d < DIM; ++d) {
    float od = fmaxf(acc[d], 0.f);
#pragma unroll
    for (int p = 0; p < NP; ++p) sc[p] = fmaf(od, keys[d * NP + p], sc[p]);
  }
#pragma unroll
  for (int p = 0; p < NP; ++p)
    sc[p] = fminf(fmaxf(sc[p], 0.f), 6.f) * L2E;   // clip, pre-scale for exp2

  // Pack 16 f32 -> 16 f16 via cvt_pkrtz (named scalars only, no scratch).
  unsigned u0 = __builtin_bit_cast(unsigned, __builtin_amdgcn_cvt_pkrtz(sc[0],  sc[1]));
  unsigned u1 = __builtin_bit_cast(unsigned, __builtin_amdgcn_cvt_pkrtz(sc[2],  sc[3]));
  unsigned u2 = __builtin_bit_cast(unsigned, __builtin_amdgcn_cvt_pkrtz(sc[4],  sc[5]));
  unsigned u3 = __builtin_bit_cast(unsigned, __builtin_amdgcn_cvt_pkrtz(sc[6],  sc[7]));
  unsigned u4 = __builtin_bit_cast(unsigned, __builtin_amdgcn_cvt_pkrtz(sc[8],  sc[9]));
  unsigned u5 = __builtin_bit_cast(unsigned, __builtin_amdgcn_cvt_pkrtz(sc[10], sc[11]));
  unsigned u6 = __builtin_bit_cast(unsigned, __builtin_amdgcn_cvt_pkrtz(sc[12], sc[13]));
  unsigned u7 = __builtin_bit_cast(unsigned, __builtin_amdgcn_cvt_pkrtz(sc[14], sc[15]));
  _Float16* dst = scoresh + ((size_t)(b >> 2) * T + t) * 64 + (b & 3) * 16;
  *(uint4*)dst       = make_uint4(u0, u1, u2, u3);
  *((uint4*)dst + 1) = make_uint4(u4, u5, u6, u7);
}

// Stage 2: speculative-parallel softmax-scan. The recurrence
// A += softmax(s-A) - 1/16 is contracting (||dA||inf non-increasing; ~15/16
// per step near the uniform attractor), so chunk c warm-ups WARM steps from
// avg0 with true scores: error ~0.9375^192 * O(10) ~ 4e-5 << threshold.
// Grid = 32 groups x 64 chunks = 2048 waves (8/CU) -> cross-wave latency
// hiding; per-wave only <=256 steps. 2-deep load pipeline in NAMED scalars
// (R1 lesson: arrays + asm memory clobber => scratch => 274 cyc/step).
__global__ void __launch_bounds__(64) scan_kernel(
    const _Float16* __restrict__ scoresh, const float* __restrict__ avg0,
    const float* __restrict__ shapes, float2* __restrict__ osd) {
  int lane = threadIdx.x;
  int g = blockIdx.x & 31;   // batch-group (4 batches)
  int c = blockIdx.x >> 5;   // chunk
  int gid = g * 64 + lane;   // = b*16 + p
  int p = lane & 15;
  int bb = gid >> 4;
  float A = avg0[gid] * L2E;
  float sh0 = shapes[2 * p];
  float sh1 = shapes[2 * p + 1];
  int w = min(WARM, c * SPC);        // c<=3 start at t=0 (exact, no spec)
  int tbeg = c * SPC - w;
  const _Float16* sp = scoresh + ((size_t)g * T + tbeg) * 64 + lane;

  float cur = (float)sp[0];
  float nxt = (float)sp[64];
  sp += 128;

  for (int i = 0; i < w; ++i) {            // warm-up: A update only
    float n2 = (float)sp[0]; sp += 64;
    float e = fexp2(cur - A);
    float r = sum16(e);
    A = fmaf(e * L2E, frcp(r), A - L2E16);
    cur = nxt; nxt = n2;
  }
  float2* od = osd + (size_t)bb * T + c * SPC;
  for (int i = 0; i < SPC; ++i) {          // committed steps
    float n2 = (float)sp[0]; sp += 64;     // (reads past end covered by pad)
    float e = fexp2(cur - A);
    float r = sum16(e);
    float rc = frcp(r);
    A = fmaf(e * L2E, rc, A - L2E16);
    float prob = e * rc;
    float o0 = sum16(prob * sh0);
    float o1 = sum16(prob * sh1);
    if (p == 0) od[i] = make_float2(o0, o1);
    cur = nxt; nxt = n2;
  }
}

// Stage 3: memory-bound elementwise. out = relu(offset + noise*std - x).
__global__ void __launch_bounds__(256) out_kernel(
    const float* __restrict__ x, const float* __restrict__ noise,
    const float2* __restrict__ osd, float* __restrict__ out) {
  size_t gid = (size_t)blockIdx.x * 256 + threadIdx.x;
  size_t i4 = gid * 4;
  int b = (int)(i4 >> 17);          // / LEN
  int l = (int)(i4 & (LEN - 1));
  int t = l >> 5;                   // window index (quad never spans t)
  float2 os = osd[(size_t)b * T + t];
  float4 xv = *(const float4*)(x + i4);
  float4 nv = *(const float4*)(noise + i4);
  float4 o;
  o.x = fmaxf(fmaf(nv.x, os.y, os.x) - xv.x, 0.f);
  o.y = fmaxf(fmaf(nv.y, os.y, os.x) - xv.y, 0.f);
  o.z = fmaxf(fmaf(nv.z, os.y, os.x) - xv.z, 0.f);
  o.w = fmaxf(fmaf(nv.w, os.y, os.x) - xv.w, 0.f);
  *(float4*)(out + i4) = o;
}

extern "C" void kernel_launch(void* const* d_in, const int* in_sizes, int n_in,
                              void* d_out, int out_size, void* d_ws, size_t ws_size,
                              hipStream_t stream) {
  const float* x      = (const float*)d_in[0];
  const float* avg0   = (const float*)d_in[1];
  const float* noise  = (const float*)d_in[2];
  const float* conv_w = (const float*)d_in[3];
  const float* conv_b = (const float*)d_in[4];
  const float* keys   = (const float*)d_in[5];
  const float* shapes = (const float*)d_in[6];
  float* out = (float*)d_out;

  _Float16* scoresh = (_Float16*)d_ws;                     // 16.78 MB
  // +1KB pad absorbs the 2-deep prefetch overrun of the last chunk.
  float2* osd = (float2*)((char*)d_ws + ((size_t)T * BATCH * NP * 2 + 1024)); // 4 MB

  scores_kernel<<<(BATCH * T) / 256, 256, 0, stream>>>(x, conv_w, conv_b, keys, scoresh);
  scan_kernel<<<32 * NCHUNK, 64, 0, stream>>>(scoresh, avg0, shapes, osd);
  out_kernel<<<(int)((size_t)BATCH * LEN / 4 / 256), 256, 0, stream>>>(x, noise, osd, out);
}

// Round 4
// 132.599 us; speedup vs baseline: 4.5447x; 1.2188x over previous
//
#include <hip/hip_runtime.h>

static constexpr int BATCH = 128;
static constexpr int LEN   = 131072;
static constexpr int T     = 4096;   // LEN / 32
static constexpr int DIM   = 32;
static constexpr int NP    = 16;

static constexpr int NCHUNK = 64;         // speculative chunks over T
static constexpr int SPC    = T / NCHUNK; // 64 steps per chunk
static constexpr int WARM   = 192;        // warm-up steps (contraction ~0.9375^192)

static constexpr int TT = 64;             // windows per scores-block

#define L2E   1.44269504088896340736f
#define L2E16 (1.44269504088896340736f / 16.0f)

typedef __attribute__((ext_vector_type(8))) short  short8;   // 8 bf16
typedef __attribute__((ext_vector_type(4))) float  f32x4;

__device__ __forceinline__ float fexp2(float x) {
#if __has_builtin(__builtin_amdgcn_exp2f)
  return __builtin_amdgcn_exp2f(x);
#else
  return exp2f(x);
#endif
}

__device__ __forceinline__ float frcp(float x) {
#if __has_builtin(__builtin_amdgcn_rcpf)
  return __builtin_amdgcn_rcpf(x);
#else
  return 1.0f / x;
#endif
}

template <int CTRL>
__device__ __forceinline__ float dppf(float v) {
  return __int_as_float(
      __builtin_amdgcn_update_dpp(0, __float_as_int(v), CTRL, 0xf, 0xf, true));
}

// Sum across each 16-lane group: butterfly over xor {1,2,7,15} via DPP.
__device__ __forceinline__ float sum16(float v) {
  v += dppf<0xB1>(v);
  v += dppf<0x4E>(v);
  v += dppf<0x141>(v);
  v += dppf<0x140>(v);
  return v;
}

// f32 -> bf16 with round-to-nearest-even (scalar cast; m240: don't hand-asm).
__device__ __forceinline__ short bf16c(float f) {
  unsigned u = __float_as_uint(f);
  unsigned r = u + 0x7fffu + ((u >> 16) & 1u);
  return (short)(r >> 16);
}

__device__ __forceinline__ short8 load_wfrag8(const float* wp) {
  float4 w0 = *(const float4*)wp;
  float4 w1 = *(const float4*)(wp + 4);
  short8 r;
  r[0] = bf16c(w0.x); r[1] = bf16c(w0.y); r[2] = bf16c(w0.z); r[3] = bf16c(w0.w);
  r[4] = bf16c(w1.x); r[5] = bf16c(w1.y); r[6] = bf16c(w1.z); r[7] = bf16c(w1.w);
  return r;
}

// Stage 1 (MFMA): block = 256 thr (4 waves) handles one b and TT=64 windows.
// conv as GEMM: A[t][k]=xbf[32t+k] (window t element k), B[k][d]=conv_w[d][k],
// 16x16x32 bf16 MFMA, K=64 in 2 steps, N=32 in 2 tiles. Then relu+bias,
// wave-private LDS transpose, one more MFMA vs keys (K=32), clip*log2e -> f16.
// Fragment layouts (m89-verified family): A row=l&15,k=(l>>4)*8+j;
// B col=l&15,k=(l>>4)*8+j; C/D col=l&15,row=(l>>4)*4+reg.
__global__ void __launch_bounds__(256) scores_kernel(
    const float* __restrict__ x, const float* __restrict__ conv_w,
    const float* __restrict__ conv_b, const float* __restrict__ keys,
    _Float16* __restrict__ scoresh) {
  __shared__ short xbf[2084];          // x[32*t0-64 .. 32*t0+2018] as bf16
  __shared__ short rlds[4][16 * 32];   // per-wave relu(conv) 16t x 32d

  int tid = threadIdx.x;
  int blk = blockIdx.x;
  int b  = blk >> 6;
  int bt = blk & 63;
  int t0 = bt * TT;
  const float* xb = x + (size_t)b * LEN;

  // ---- stage x -> bf16 LDS. LDS idx i <-> global 32*t0-63+i (i = 4*j-1+e).
#pragma unroll
  for (int s = 0; s < 2; ++s) {
    int jj = 2 * tid + s;
    int gi = 32 * t0 - 64 + 4 * jj;
    float4 v = make_float4(0.f, 0.f, 0.f, 0.f);
    if (gi >= 0) v = *(const float4*)(xb + gi);
    int li = 4 * jj - 1;
    if (li >= 0) xbf[li] = bf16c(v.x);
    xbf[li + 1] = bf16c(v.y);
    xbf[li + 2] = bf16c(v.z);
    xbf[li + 3] = bf16c(v.w);
  }
  if (tid < 9) {                      // tail: LDS 2047..2082
    int jj = 512 + tid;
    int gi = 32 * t0 - 64 + 4 * jj;   // max read gi+3 = 32*t0+2019 < LEN
    float4 v = *(const float4*)(xb + gi);
    int li = 4 * jj - 1;
    xbf[li]     = bf16c(v.x);
    xbf[li + 1] = bf16c(v.y);
    xbf[li + 2] = bf16c(v.z);
    xbf[li + 3] = bf16c(v.w);
  }

  int lane = tid & 63;
  int mt   = tid >> 6;     // wave = M-tile (16 windows)
  int ln15 = lane & 15;
  int kg   = lane >> 4;    // 0..3

  // conv-weight B-frags (global, L2-hot): d = nt*16+ln15, k = ks*32+kg*8+j
  short8 bw00 = load_wfrag8(conv_w + (0 * 16 + ln15) * 64 + 0 * 32 + kg * 8);
  short8 bw01 = load_wfrag8(conv_w + (0 * 16 + ln15) * 64 + 1 * 32 + kg * 8);
  short8 bw10 = load_wfrag8(conv_w + (1 * 16 + ln15) * 64 + 0 * 32 + kg * 8);
  short8 bw11 = load_wfrag8(conv_w + (1 * 16 + ln15) * 64 + 1 * 32 + kg * 8);
  // keys B-frag: p = ln15, d(k) = kg*8+j
  short8 bk;
#pragma unroll
  for (int j = 0; j < 8; ++j) bk[j] = bf16c(keys[(kg * 8 + j) * NP + ln15]);
  float bias0 = conv_b[ln15];
  float bias1 = conv_b[16 + ln15];

  __syncthreads();

  // A-frags from xbf: t_local = mt*16 + ln15, k = ks*32 + kg*8 (+j)
  const short* ap = &xbf[32 * (mt * 16 + ln15)];
  short8 a0 = *(const short8*)(ap + 0 * 32 + kg * 8);
  short8 a1 = *(const short8*)(ap + 1 * 32 + kg * 8);

  f32x4 acc0 = {0.f, 0.f, 0.f, 0.f};
  f32x4 acc1 = {0.f, 0.f, 0.f, 0.f};
  acc0 = __builtin_amdgcn_mfma_f32_16x16x32_bf16(a0, bw00, acc0, 0, 0, 0);
  acc0 = __builtin_amdgcn_mfma_f32_16x16x32_bf16(a1, bw01, acc0, 0, 0, 0);
  acc1 = __builtin_amdgcn_mfma_f32_16x16x32_bf16(a0, bw10, acc1, 0, 0, 0);
  acc1 = __builtin_amdgcn_mfma_f32_16x16x32_bf16(a1, bw11, acc1, 0, 0, 0);

  // relu(conv+bias) -> bf16 -> wave-private LDS [t][d] (transpose for MFMA2)
  short* rl = rlds[mt];
#pragma unroll
  for (int r = 0; r < 4; ++r) {
    int trow = kg * 4 + r;                     // D row = (l>>4)*4 + r
    rl[trow * 32 + ln15]      = bf16c(fmaxf(acc0[r] + bias0, 0.f));
    rl[trow * 32 + 16 + ln15] = bf16c(fmaxf(acc1[r] + bias1, 0.f));
  }
  __syncthreads();   // also orders the cross-lane LDS writes before reads

  // A2-frag: t = ln15, d = kg*8+j  (contiguous 16B, aligned)
  short8 a2 = *(const short8*)(&rl[ln15 * 32 + kg * 8]);
  f32x4 acc2 = {0.f, 0.f, 0.f, 0.f};
  acc2 = __builtin_amdgcn_mfma_f32_16x16x32_bf16(a2, bk, acc2, 0, 0, 0);

  // D2: p = ln15, t = t0 + mt*16 + kg*4 + r. clip*log2e -> f16 store.
  _Float16* dstb = scoresh + (b & 3) * 16 + ln15;
#pragma unroll
  for (int r = 0; r < 4; ++r) {
    float s = fminf(fmaxf(acc2[r], 0.f), 6.f) * L2E;
    int t = t0 + mt * 16 + kg * 4 + r;
    dstb[((size_t)(b >> 2) * T + t) * 64] = (_Float16)s;
  }
}

// Stage 2: speculative-parallel softmax-scan (R2; contraction ~15/16 per
// step => WARM=192 warm-up from avg0 gives ~4e-5 speculation error).
__global__ void __launch_bounds__(64) scan_kernel(
    const _Float16* __restrict__ scoresh, const float* __restrict__ avg0,
    const float* __restrict__ shapes, float2* __restrict__ osd) {
  int lane = threadIdx.x;
  int g = blockIdx.x & 31;   // batch-group (4 batches)
  int c = blockIdx.x >> 5;   // chunk
  int gid = g * 64 + lane;   // = b*16 + p
  int p = lane & 15;
  int bb = gid >> 4;
  float A = avg0[gid] * L2E;
  float sh0 = shapes[2 * p];
  float sh1 = shapes[2 * p + 1];
  int w = min(WARM, c * SPC);        // first chunks start exact at t=0
  int tbeg = c * SPC - w;
  const _Float16* sp = scoresh + ((size_t)g * T + tbeg) * 64 + lane;

  float cur = (float)sp[0];
  float nxt = (float)sp[64];
  sp += 128;

  for (int i = 0; i < w; ++i) {            // warm-up: A update only
    float n2 = (float)sp[0]; sp += 64;
    float e = fexp2(cur - A);
    float r = sum16(e);
    A = fmaf(e * L2E, frcp(r), A - L2E16);
    cur = nxt; nxt = n2;
  }
  float2* od = osd + (size_t)bb * T + c * SPC;
  for (int i = 0; i < SPC; ++i) {          // committed steps
    float n2 = (float)sp[0]; sp += 64;     // overrun covered by ws pad
    float e = fexp2(cur - A);
    float r = sum16(e);
    float rc = frcp(r);
    A = fmaf(e * L2E, rc, A - L2E16);
    float prob = e * rc;
    float o0 = sum16(prob * sh0);
    float o1 = sum16(prob * sh1);
    if (p == 0) od[i] = make_float2(o0, o1);
    cur = nxt; nxt = n2;
  }
}

// Stage 3: memory-bound elementwise. out = relu(offset + noise*std - x).
__global__ void __launch_bounds__(256) out_kernel(
    const float* __restrict__ x, const float* __restrict__ noise,
    const float2* __restrict__ osd, float* __restrict__ out) {
  size_t gid = (size_t)blockIdx.x * 256 + threadIdx.x;
  size_t i4 = gid * 4;
  int b = (int)(i4 >> 17);          // / LEN
  int l = (int)(i4 & (LEN - 1));
  int t = l >> 5;                   // window index (quad never spans t)
  float2 os = osd[(size_t)b * T + t];
  float4 xv = *(const float4*)(x + i4);
  float4 nv = *(const float4*)(noise + i4);
  float4 o;
  o.x = fmaxf(fmaf(nv.x, os.y, os.x) - xv.x, 0.f);
  o.y = fmaxf(fmaf(nv.y, os.y, os.x) - xv.y, 0.f);
  o.z = fmaxf(fmaf(nv.z, os.y, os.x) - xv.z, 0.f);
  o.w = fmaxf(fmaf(nv.w, os.y, os.x) - xv.w, 0.f);
  *(float4*)(out + i4) = o;
}

extern "C" void kernel_launch(void* const* d_in, const int* in_sizes, int n_in,
                              void* d_out, int out_size, void* d_ws, size_t ws_size,
                              hipStream_t stream) {
  const float* x      = (const float*)d_in[0];
  const float* avg0   = (const float*)d_in[1];
  const float* noise  = (const float*)d_in[2];
  const float* conv_w = (const float*)d_in[3];
  const float* conv_b = (const float*)d_in[4];
  const float* keys   = (const float*)d_in[5];
  const float* shapes = (const float*)d_in[6];
  float* out = (float*)d_out;

  _Float16* scoresh = (_Float16*)d_ws;                     // 16.78 MB
  // +1KB pad absorbs the 2-deep prefetch overrun of the last chunk.
  float2* osd = (float2*)((char*)d_ws + ((size_t)T * BATCH * NP * 2 + 1024)); // 4 MB

  scores_kernel<<<BATCH * (T / TT), 256, 0, stream>>>(x, conv_w, conv_b, keys, scoresh);
  scan_kernel<<<32 * NCHUNK, 64, 0, stream>>>(scoresh, avg0, shapes, osd);
  out_kernel<<<(int)((size_t)BATCH * LEN / 4 / 256), 256, 0, stream>>>(x, noise, osd, out);
}

// Round 5
// 98.746 us; speedup vs baseline: 6.1027x; 1.3428x over previous
//
#include <hip/hip_runtime.h>

static constexpr int BATCH = 128;
static constexpr int LEN   = 131072;
static constexpr int T     = 4096;   // LEN / 32
static constexpr int DIM   = 32;
static constexpr int NP    = 16;

static constexpr int NCHUNK = 64;         // speculative chunks over T
static constexpr int SPC    = T / NCHUNK; // 64 steps per chunk
static constexpr int WARM   = 160;        // warm-up steps (0.9375^160 ~ 3e-5)

static constexpr int TT = 64;             // windows per scores-block

#define L2E   1.44269504088896340736f
#define L2E16 (1.44269504088896340736f / 16.0f)

typedef __attribute__((ext_vector_type(8))) short  short8;   // 8 bf16
typedef __attribute__((ext_vector_type(4))) float  f32x4;

__device__ __forceinline__ float fexp2(float x) {
#if __has_builtin(__builtin_amdgcn_exp2f)
  return __builtin_amdgcn_exp2f(x);
#else
  return exp2f(x);
#endif
}

__device__ __forceinline__ float frcp(float x) {
#if __has_builtin(__builtin_amdgcn_rcpf)
  return __builtin_amdgcn_rcpf(x);
#else
  return 1.0f / x;
#endif
}

template <int CTRL>
__device__ __forceinline__ float dppf(float v) {
  return __int_as_float(
      __builtin_amdgcn_update_dpp(0, __float_as_int(v), CTRL, 0xf, 0xf, true));
}

// Sum across each 16-lane group: butterfly over xor {1,2,7,15} via DPP.
__device__ __forceinline__ float sum16(float v) {
  v += dppf<0xB1>(v);
  v += dppf<0x4E>(v);
  v += dppf<0x141>(v);
  v += dppf<0x140>(v);
  return v;
}

// f32 -> bf16 round-to-nearest-even.
__device__ __forceinline__ short bf16c(float f) {
  unsigned u = __float_as_uint(f);
  unsigned r = u + 0x7fffu + ((u >> 16) & 1u);
  return (short)(r >> 16);
}

__device__ __forceinline__ short8 load_wfrag8(const float* wp) {
  float4 w0 = *(const float4*)wp;
  float4 w1 = *(const float4*)(wp + 4);
  short8 r;
  r[0] = bf16c(w0.x); r[1] = bf16c(w0.y); r[2] = bf16c(w0.z); r[3] = bf16c(w0.w);
  r[4] = bf16c(w1.x); r[5] = bf16c(w1.y); r[6] = bf16c(w1.z); r[7] = bf16c(w1.w);
  return r;
}

// Stage 1 (MFMA): block = 256 thr (4 waves) handles one b and TT=64 windows.
// conv as GEMM via 16x16x32 bf16 MFMA (K=64 in 2 steps, N=32 in 2 tiles),
// relu+bias in D-layout, wave-private LDS transpose, MFMA vs keys (K=32).
// Fragment layouts (m89-verified): A row=l&15,k=(l>>4)*8+j; B col=l&15,
// same k; C/D col=l&15, row=(l>>4)*4+reg.
__global__ void __launch_bounds__(256) scores_kernel(
    const float* __restrict__ x, const float* __restrict__ conv_w,
    const float* __restrict__ conv_b, const float* __restrict__ keys,
    _Float16* __restrict__ scoresh) {
  __shared__ short xbf[2084];          // x[32*t0-64 .. 32*t0+2018] as bf16
  __shared__ short rlds[4][16 * 32];   // per-wave relu(conv) 16t x 32d

  int tid = threadIdx.x;
  int blk = blockIdx.x;
  int b  = blk >> 6;
  int bt = blk & 63;
  int t0 = bt * TT;
  const float* xb = x + (size_t)b * LEN;

  // ---- stage x -> bf16 LDS. LDS idx i <-> global 32*t0-63+i.
#pragma unroll
  for (int s = 0; s < 2; ++s) {
    int jj = 2 * tid + s;
    int gi = 32 * t0 - 64 + 4 * jj;
    float4 v = make_float4(0.f, 0.f, 0.f, 0.f);
    if (gi >= 0) v = *(const float4*)(xb + gi);
    int li = 4 * jj - 1;
    if (li >= 0) xbf[li] = bf16c(v.x);
    xbf[li + 1] = bf16c(v.y);
    xbf[li + 2] = bf16c(v.z);
    xbf[li + 3] = bf16c(v.w);
  }
  if (tid < 9) {                      // tail: LDS 2047..2082
    int jj = 512 + tid;
    int gi = 32 * t0 - 64 + 4 * jj;   // max read gi+3 = 32*t0+2019 < LEN
    float4 v = *(const float4*)(xb + gi);
    int li = 4 * jj - 1;
    xbf[li]     = bf16c(v.x);
    xbf[li + 1] = bf16c(v.y);
    xbf[li + 2] = bf16c(v.z);
    xbf[li + 3] = bf16c(v.w);
  }

  int lane = tid & 63;
  int mt   = tid >> 6;     // wave = M-tile (16 windows)
  int ln15 = lane & 15;
  int kg   = lane >> 4;    // 0..3

  // conv-weight B-frags: d = nt*16+ln15, k = ks*32+kg*8+j
  short8 bw00 = load_wfrag8(conv_w + (0 * 16 + ln15) * 64 + 0 * 32 + kg * 8);
  short8 bw01 = load_wfrag8(conv_w + (0 * 16 + ln15) * 64 + 1 * 32 + kg * 8);
  short8 bw10 = load_wfrag8(conv_w + (1 * 16 + ln15) * 64 + 0 * 32 + kg * 8);
  short8 bw11 = load_wfrag8(conv_w + (1 * 16 + ln15) * 64 + 1 * 32 + kg * 8);
  // keys B-frag: p = ln15, k(d) = kg*8+j
  short8 bk;
#pragma unroll
  for (int j = 0; j < 8; ++j) bk[j] = bf16c(keys[(kg * 8 + j) * NP + ln15]);
  float bias0 = conv_b[ln15];
  float bias1 = conv_b[16 + ln15];

  __syncthreads();

  // A-frags from xbf: t_local = mt*16 + ln15, k = ks*32 + kg*8 (+j)
  const short* ap = &xbf[32 * (mt * 16 + ln15)];
  short8 a0 = *(const short8*)(ap + 0 * 32 + kg * 8);
  short8 a1 = *(const short8*)(ap + 1 * 32 + kg * 8);

  f32x4 acc0 = {0.f, 0.f, 0.f, 0.f};
  f32x4 acc1 = {0.f, 0.f, 0.f, 0.f};
  acc0 = __builtin_amdgcn_mfma_f32_16x16x32_bf16(a0, bw00, acc0, 0, 0, 0);
  acc0 = __builtin_amdgcn_mfma_f32_16x16x32_bf16(a1, bw01, acc0, 0, 0, 0);
  acc1 = __builtin_amdgcn_mfma_f32_16x16x32_bf16(a0, bw10, acc1, 0, 0, 0);
  acc1 = __builtin_amdgcn_mfma_f32_16x16x32_bf16(a1, bw11, acc1, 0, 0, 0);

  // relu(conv+bias) -> bf16 -> wave-private LDS [t][d] (transpose for MFMA2)
  short* rl = rlds[mt];
#pragma unroll
  for (int r = 0; r < 4; ++r) {
    int trow = kg * 4 + r;                     // D row = (l>>4)*4 + r
    rl[trow * 32 + ln15]      = bf16c(fmaxf(acc0[r] + bias0, 0.f));
    rl[trow * 32 + 16 + ln15] = bf16c(fmaxf(acc1[r] + bias1, 0.f));
  }
  __syncthreads();

  // A2-frag: t = ln15, d = kg*8+j  (contiguous 16B, aligned)
  short8 a2 = *(const short8*)(&rl[ln15 * 32 + kg * 8]);
  f32x4 acc2 = {0.f, 0.f, 0.f, 0.f};
  acc2 = __builtin_amdgcn_mfma_f32_16x16x32_bf16(a2, bk, acc2, 0, 0, 0);

  // D2: p = ln15, t = t0 + mt*16 + kg*4 + r. clip*log2e -> f16 store.
  _Float16* dstb = scoresh + (b & 3) * 16 + ln15;
#pragma unroll
  for (int r = 0; r < 4; ++r) {
    float s = fminf(fmaxf(acc2[r], 0.f), 6.f) * L2E;
    int t = t0 + mt * 16 + kg * 4 + r;
    dstb[((size_t)(b >> 2) * T + t) * 64] = (_Float16)s;
  }
}

// Stage 2: speculative-parallel softmax-scan with an 8-deep register
// prefetch pipeline (named scalars q0..q7, unroll-by-8 -> pure register
// rotation; R1/R3 lesson: arrays or shallow pipelines expose memory latency
// on the serial chain). Commit steps use the group-uniformity of rc=1/sum(e):
// o = rc*sum16(e*sh), so all three sum16 butterflies run in parallel.
__global__ void __launch_bounds__(64) scan_kernel(
    const _Float16* __restrict__ scoresh, const float* __restrict__ avg0,
    const float* __restrict__ shapes, float2* __restrict__ osd) {
  int lane = threadIdx.x;
  int g = blockIdx.x & 31;   // batch-group (4 batches)
  int c = blockIdx.x >> 5;   // chunk
  int gid = g * 64 + lane;   // = b*16 + p
  int p = lane & 15;
  int bb = gid >> 4;
  float A = avg0[gid] * L2E;
  float sh0 = shapes[2 * p];
  float sh1 = shapes[2 * p + 1];
  int w = min(WARM, c * SPC);        // c=0 exact; w in {0,64,128,160} (%8==0)
  int tbeg = c * SPC - w;
  const _Float16* sp = scoresh + ((size_t)g * T + tbeg) * 64 + lane;

  float q0 = (float)sp[0 * 64];
  float q1 = (float)sp[1 * 64];
  float q2 = (float)sp[2 * 64];
  float q3 = (float)sp[3 * 64];
  float q4 = (float)sp[4 * 64];
  float q5 = (float)sp[5 * 64];
  float q6 = (float)sp[6 * 64];
  float q7 = (float)sp[7 * 64];
  sp += 8 * 64;

#define WSTEP(Q)                                   \
  do {                                             \
    float e = fexp2(Q - A);                        \
    float r = sum16(e);                            \
    A = fmaf(e * L2E, frcp(r), A - L2E16);         \
    Q = (float)sp[0];                              \
    sp += 64;                                      \
  } while (0)

  for (int i = 0; i < w; i += 8) {
    WSTEP(q0); WSTEP(q1); WSTEP(q2); WSTEP(q3);
    WSTEP(q4); WSTEP(q5); WSTEP(q6); WSTEP(q7);
  }

  float2* od = osd + (size_t)bb * T + c * SPC;
#define CSTEP(Q, idx)                              \
  do {                                             \
    float e = fexp2(Q - A);                        \
    float r  = sum16(e);                           \
    float u0 = sum16(e * sh0);                     \
    float u1 = sum16(e * sh1);                     \
    float rc = frcp(r);                            \
    A = fmaf(e * L2E, rc, A - L2E16);              \
    if (p == 0) od[idx] = make_float2(u0 * rc, u1 * rc); \
    Q = (float)sp[0];                              \
    sp += 64;                                      \
  } while (0)

  for (int i = 0; i < SPC; i += 8) {               // prefetch overrun <= 1KB pad
    CSTEP(q0, i + 0); CSTEP(q1, i + 1); CSTEP(q2, i + 2); CSTEP(q3, i + 3);
    CSTEP(q4, i + 4); CSTEP(q5, i + 5); CSTEP(q6, i + 6); CSTEP(q7, i + 7);
  }
#undef WSTEP
#undef CSTEP
}

// Stage 3: memory-bound elementwise. out = relu(offset + noise*std - x).
__global__ void __launch_bounds__(256) out_kernel(
    const float* __restrict__ x, const float* __restrict__ noise,
    const float2* __restrict__ osd, float* __restrict__ out) {
  size_t gid = (size_t)blockIdx.x * 256 + threadIdx.x;
  size_t i4 = gid * 4;
  int b = (int)(i4 >> 17);          // / LEN
  int l = (int)(i4 & (LEN - 1));
  int t = l >> 5;                   // window index (quad never spans t)
  float2 os = osd[(size_t)b * T + t];
  float4 xv = *(const float4*)(x + i4);
  float4 nv = *(const float4*)(noise + i4);
  float4 o;
  o.x = fmaxf(fmaf(nv.x, os.y, os.x) - xv.x, 0.f);
  o.y = fmaxf(fmaf(nv.y, os.y, os.x) - xv.y, 0.f);
  o.z = fmaxf(fmaf(nv.z, os.y, os.x) - xv.z, 0.f);
  o.w = fmaxf(fmaf(nv.w, os.y, os.x) - xv.w, 0.f);
  *(float4*)(out + i4) = o;
}

extern "C" void kernel_launch(void* const* d_in, const int* in_sizes, int n_in,
                              void* d_out, int out_size, void* d_ws, size_t ws_size,
                              hipStream_t stream) {
  const float* x      = (const float*)d_in[0];
  const float* avg0   = (const float*)d_in[1];
  const float* noise  = (const float*)d_in[2];
  const float* conv_w = (const float*)d_in[3];
  const float* conv_b = (const float*)d_in[4];
  const float* keys   = (const float*)d_in[5];
  const float* shapes = (const float*)d_in[6];
  float* out = (float*)d_out;

  _Float16* scoresh = (_Float16*)d_ws;                     // 16.78 MB
  // +1KB pad absorbs the 8-deep prefetch overrun of the last chunk.
  float2* osd = (float2*)((char*)d_ws + ((size_t)T * BATCH * NP * 2 + 1024)); // 4 MB

  scores_kernel<<<BATCH * (T / TT), 256, 0, stream>>>(x, conv_w, conv_b, keys, scoresh);
  scan_kernel<<<32 * NCHUNK, 64, 0, stream>>>(scoresh, avg0, shapes, osd);
  out_kernel<<<(int)((size_t)BATCH * LEN / 4 / 256), 256, 0, stream>>>(x, noise, osd, out);
}

// Round 6
// 81.333 us; speedup vs baseline: 7.4093x; 1.2141x over previous
//
#include <hip/hip_runtime.h>

static constexpr int BATCH = 128;
static constexpr int LEN   = 131072;
static constexpr int T     = 4096;   // LEN / 32
static constexpr int DIM   = 32;
static constexpr int NP    = 16;

static constexpr int NCHUNK = 64;         // speculative chunks over T
static constexpr int SPC    = T / NCHUNK; // 64 steps per chunk
static constexpr int WARM   = 160;        // warm-up steps (0.9375^160 ~ 3e-5)

static constexpr int TT = 128;            // windows per scores-block

#define L2E   1.44269504088896340736f
#define L2E16 (1.44269504088896340736f / 16.0f)

typedef __attribute__((ext_vector_type(8))) short  short8;   // 8 bf16
typedef __attribute__((ext_vector_type(4))) float  f32x4;

__device__ __forceinline__ float fexp2(float x) {
#if __has_builtin(__builtin_amdgcn_exp2f)
  return __builtin_amdgcn_exp2f(x);
#else
  return exp2f(x);
#endif
}

__device__ __forceinline__ float frcp(float x) {
#if __has_builtin(__builtin_amdgcn_rcpf)
  return __builtin_amdgcn_rcpf(x);
#else
  return 1.0f / x;
#endif
}

template <int CTRL>
__device__ __forceinline__ float dppf(float v) {
  return __int_as_float(
      __builtin_amdgcn_update_dpp(0, __float_as_int(v), CTRL, 0xf, 0xf, true));
}

// Sum across each 16-lane group: butterfly over xor {1,2,7,15} via DPP.
__device__ __forceinline__ float sum16(float v) {
  v += dppf<0xB1>(v);
  v += dppf<0x4E>(v);
  v += dppf<0x141>(v);
  v += dppf<0x140>(v);
  return v;
}

// f32 -> bf16 round-to-nearest-even.
__device__ __forceinline__ short bf16c(float f) {
  unsigned u = __float_as_uint(f);
  unsigned r = u + 0x7fffu + ((u >> 16) & 1u);
  return (short)(r >> 16);
}

// One-shot prep: build bf16 MFMA fragments for conv_w / keys / bias in the
// exact per-lane layout scores_kernel consumes (R4 post-mortem: re-converting
// f32 weights per block was ~130 VALU ops x 8192 blocks of pure waste).
// Layout (shorts): [fs=fn*2+fk][lane][8] (4x1KB), then kfrag [lane][8] (1KB),
// then bias as float2[lane] (512B). Total 5.6KB -> L1-resident.
__global__ void __launch_bounds__(64) prep_kernel(
    const float* __restrict__ conv_w, const float* __restrict__ conv_b,
    const float* __restrict__ keys, short* __restrict__ frags) {
  int l = threadIdx.x;
  int ln15 = l & 15, kg = l >> 4;
#pragma unroll
  for (int fn = 0; fn < 2; ++fn)
#pragma unroll
    for (int fk = 0; fk < 2; ++fk) {
      const float* wp = conv_w + (fn * 16 + ln15) * 64 + fk * 32 + kg * 8;
      short* dst = frags + ((fn * 2 + fk) * 64 + l) * 8;
#pragma unroll
      for (int j = 0; j < 8; ++j) dst[j] = bf16c(wp[j]);
    }
  short* kd = frags + (256 + l) * 8;
#pragma unroll
  for (int j = 0; j < 8; ++j) kd[j] = bf16c(keys[(kg * 8 + j) * NP + ln15]);
  float* bp = (float*)(frags + 2560);
  bp[2 * l]     = conv_b[ln15];
  bp[2 * l + 1] = conv_b[16 + ln15];
}

// Stage 1 (MFMA): block = 256 thr (4 waves), one b, TT=128 windows; each wave
// runs 2 sequential 16-window M-tiles. conv as GEMM via 16x16x32 bf16 MFMA
// (K=64 in 2 steps, N=32 in 2 tiles), relu+bias in D-layout, wave-private LDS
// transpose (same-wave DS ops are in-order -> no barrier), MFMA vs keys.
// Fragment layouts (m89-verified): A row=l&15,k=(l>>4)*8+j; B col=l&15,
// same k; C/D col=l&15, row=(l>>4)*4+reg.
__global__ void __launch_bounds__(256) scores_kernel(
    const float* __restrict__ x, const short* __restrict__ frags,
    _Float16* __restrict__ scoresh) {
  __shared__ short xbf[4144];          // x[32*t0-63 .. 32*t0+4067] as bf16
  __shared__ short rlds[4][16 * 32];   // per-wave relu(conv) 16t x 32d

  int tid = threadIdx.x;
  int blk = blockIdx.x;
  int b  = blk >> 5;
  int bt = blk & 31;
  int t0 = bt * TT;
  const float* xb = x + (size_t)b * LEN;

  // ---- stage x -> bf16 LDS. xbf[li] = x[32*t0-63+li].
  // Thread: 16 contiguous floats (4 aligned quads) + 1 scalar -> 2x b128 + 1x b16.
  int gbase = 32 * t0 - 64 + 16 * tid;
  float f[17];
#pragma unroll
  for (int s = 0; s < 4; ++s) {
    int gi = gbase + 4 * s;
    float4 v = make_float4(0.f, 0.f, 0.f, 0.f);
    if (gi >= 0) v = *(const float4*)(xb + gi);
    f[4 * s]     = v.x; f[4 * s + 1] = v.y;
    f[4 * s + 2] = v.z; f[4 * s + 3] = v.w;
  }
  f[16] = (gbase + 16 >= 0) ? xb[gbase + 16] : 0.f;

  short8 w0, w1;
#pragma unroll
  for (int j = 0; j < 8; ++j) { w0[j] = bf16c(f[j + 1]); w1[j] = bf16c(f[j + 9]); }
  *(short8*)(&xbf[16 * tid])     = w0;
  *(short8*)(&xbf[16 * tid + 8]) = w1;
  if (tid > 0) xbf[16 * tid - 1] = bf16c(f[0]);
  if (tid < 9) {                       // tail: li 4095..4130
    int gi = 32 * t0 + 4032 + 4 * tid; // max read gi+3 = 32*t0+4067 < LEN
    float4 v = *(const float4*)(xb + gi);
    int li = 4095 + 4 * tid;
    xbf[li]     = bf16c(v.x);
    xbf[li + 1] = bf16c(v.y);
    xbf[li + 2] = bf16c(v.z);
    xbf[li + 3] = bf16c(v.w);
  }

  int lane = tid & 63;
  int mt   = tid >> 6;     // wave id
  int ln15 = lane & 15;
  int kg   = lane >> 4;    // 0..3

  // Prebuilt fragments: 5x16B + 8B, coalesced, L1-hot after first block.
  const short8* wf = (const short8*)frags;
  short8 bw00 = wf[0 * 64 + lane];
  short8 bw01 = wf[1 * 64 + lane];
  short8 bw10 = wf[2 * 64 + lane];
  short8 bw11 = wf[3 * 64 + lane];
  short8 bk   = wf[4 * 64 + lane];
  const float2* bp = (const float2*)(frags + 2560);
  float2 bias = bp[lane];

  __syncthreads();

  short* rl = rlds[mt];
  _Float16* dstb = scoresh + (b & 3) * 16 + ln15;

#pragma unroll
  for (int st = 0; st < 2; ++st) {
    int tl0 = mt * 32 + st * 16 + ln15;          // window row for A-frag
    const short* ap = &xbf[32 * tl0];
    short8 a0 = *(const short8*)(ap + kg * 8);
    short8 a1 = *(const short8*)(ap + 32 + kg * 8);

    f32x4 acc0 = {0.f, 0.f, 0.f, 0.f};
    f32x4 acc1 = {0.f, 0.f, 0.f, 0.f};
    acc0 = __builtin_amdgcn_mfma_f32_16x16x32_bf16(a0, bw00, acc0, 0, 0, 0);
    acc0 = __builtin_amdgcn_mfma_f32_16x16x32_bf16(a1, bw01, acc0, 0, 0, 0);
    acc1 = __builtin_amdgcn_mfma_f32_16x16x32_bf16(a0, bw10, acc1, 0, 0, 0);
    acc1 = __builtin_amdgcn_mfma_f32_16x16x32_bf16(a1, bw11, acc1, 0, 0, 0);

    // relu(conv+bias) -> bf16 -> wave-private LDS [t][d] (transpose).
#pragma unroll
    for (int r = 0; r < 4; ++r) {
      int trow = kg * 4 + r;                     // D row = (l>>4)*4 + r
      rl[trow * 32 + ln15]      = bf16c(fmaxf(acc0[r] + bias.x, 0.f));
      rl[trow * 32 + 16 + ln15] = bf16c(fmaxf(acc1[r] + bias.y, 0.f));
    }
    // Same-wave DS ops are in-order: reads below see the writes above; the
    // next st's writes can't pass this read either (WAR safe). No barrier.
    short8 a2 = *(const short8*)(&rl[ln15 * 32 + kg * 8]);
    f32x4 acc2 = {0.f, 0.f, 0.f, 0.f};
    acc2 = __builtin_amdgcn_mfma_f32_16x16x32_bf16(a2, bk, acc2, 0, 0, 0);

    // D2: p = ln15, t = t0 + mt*32 + st*16 + kg*4 + r. clip*log2e -> f16.
#pragma unroll
    for (int r = 0; r < 4; ++r) {
      float s = fminf(fmaxf(acc2[r], 0.f), 6.f) * L2E;
      int t = t0 + mt * 32 + st * 16 + kg * 4 + r;
      dstb[((size_t)(b >> 2) * T + t) * 64] = (_Float16)s;
    }
  }
}

// Stage 2: speculative-parallel softmax-scan, 8-deep register prefetch in
// named scalars (R3/R4). Commit steps exploit group-uniform rc = 1/sum(e):
// o = rc*sum16(e*sh) -> the three sum16 butterflies run in parallel.
__global__ void __launch_bounds__(64) scan_kernel(
    const _Float16* __restrict__ scoresh, const float* __restrict__ avg0,
    const float* __restrict__ shapes, float2* __restrict__ osd) {
  int lane = threadIdx.x;
  int g = blockIdx.x & 31;   // batch-group (4 batches)
  int c = blockIdx.x >> 5;   // chunk
  int gid = g * 64 + lane;   // = b*16 + p
  int p = lane & 15;
  int bb = gid >> 4;
  float A = avg0[gid] * L2E;
  float sh0 = shapes[2 * p];
  float sh1 = shapes[2 * p + 1];
  int w = min(WARM, c * SPC);        // c=0 exact; w in {0,64,128,160} (%8==0)
  int tbeg = c * SPC - w;
  const _Float16* sp = scoresh + ((size_t)g * T + tbeg) * 64 + lane;

  float q0 = (float)sp[0 * 64];
  float q1 = (float)sp[1 * 64];
  float q2 = (float)sp[2 * 64];
  float q3 = (float)sp[3 * 64];
  float q4 = (float)sp[4 * 64];
  float q5 = (float)sp[5 * 64];
  float q6 = (float)sp[6 * 64];
  float q7 = (float)sp[7 * 64];
  sp += 8 * 64;

#define WSTEP(Q)                                   \
  do {                                             \
    float e = fexp2(Q - A);                        \
    float r = sum16(e);                            \
    A = fmaf(e * L2E, frcp(r), A - L2E16);         \
    Q = (float)sp[0];                              \
    sp += 64;                                      \
  } while (0)

  for (int i = 0; i < w; i += 8) {
    WSTEP(q0); WSTEP(q1); WSTEP(q2); WSTEP(q3);
    WSTEP(q4); WSTEP(q5); WSTEP(q6); WSTEP(q7);
  }

  float2* od = osd + (size_t)bb * T + c * SPC;
#define CSTEP(Q, idx)                              \
  do {                                             \
    float e = fexp2(Q - A);                        \
    float r  = sum16(e);                           \
    float u0 = sum16(e * sh0);                     \
    float u1 = sum16(e * sh1);                     \
    float rc = frcp(r);                            \
    A = fmaf(e * L2E, rc, A - L2E16);              \
    if (p == 0) od[idx] = make_float2(u0 * rc, u1 * rc); \
    Q = (float)sp[0];                              \
    sp += 64;                                      \
  } while (0)

  for (int i = 0; i < SPC; i += 8) {               // prefetch overrun <= 1KB pad
    CSTEP(q0, i + 0); CSTEP(q1, i + 1); CSTEP(q2, i + 2); CSTEP(q3, i + 3);
    CSTEP(q4, i + 4); CSTEP(q5, i + 5); CSTEP(q6, i + 6); CSTEP(q7, i + 7);
  }
#undef WSTEP
#undef CSTEP
}

// Stage 3: memory-bound elementwise. out = relu(offset + noise*std - x).
// Already ~97% of achievable HBM BW (201MB @ ~33us).
__global__ void __launch_bounds__(256) out_kernel(
    const float* __restrict__ x, const float* __restrict__ noise,
    const float2* __restrict__ osd, float* __restrict__ out) {
  size_t gid = (size_t)blockIdx.x * 256 + threadIdx.x;
  size_t i4 = gid * 4;
  int b = (int)(i4 >> 17);          // / LEN
  int l = (int)(i4 & (LEN - 1));
  int t = l >> 5;                   // window index (quad never spans t)
  float2 os = osd[(size_t)b * T + t];
  float4 xv = *(const float4*)(x + i4);
  float4 nv = *(const float4*)(noise + i4);
  float4 o;
  o.x = fmaxf(fmaf(nv.x, os.y, os.x) - xv.x, 0.f);
  o.y = fmaxf(fmaf(nv.y, os.y, os.x) - xv.y, 0.f);
  o.z = fmaxf(fmaf(nv.z, os.y, os.x) - xv.z, 0.f);
  o.w = fmaxf(fmaf(nv.w, os.y, os.x) - xv.w, 0.f);
  *(float4*)(out + i4) = o;
}

extern "C" void kernel_launch(void* const* d_in, const int* in_sizes, int n_in,
                              void* d_out, int out_size, void* d_ws, size_t ws_size,
                              hipStream_t stream) {
  const float* x      = (const float*)d_in[0];
  const float* avg0   = (const float*)d_in[1];
  const float* noise  = (const float*)d_in[2];
  const float* conv_w = (const float*)d_in[3];
  const float* conv_b = (const float*)d_in[4];
  const float* keys   = (const float*)d_in[5];
  const float* shapes = (const float*)d_in[6];
  float* out = (float*)d_out;

  _Float16* scoresh = (_Float16*)d_ws;                               // 16.78 MB
  // +1KB pad absorbs the 8-deep prefetch overrun of the last chunk.
  char* p1 = (char*)d_ws + ((size_t)T * BATCH * NP * 2 + 1024);
  float2* osd = (float2*)p1;                                          // 4 MB
  short* frags = (short*)(p1 + (size_t)BATCH * T * 8);                // 5.6 KB

  prep_kernel<<<1, 64, 0, stream>>>(conv_w, conv_b, keys, frags);
  scores_kernel<<<BATCH * (T / TT), 256, 0, stream>>>(x, frags, scoresh);
  scan_kernel<<<32 * NCHUNK, 64, 0, stream>>>(scoresh, avg0, shapes, osd);
  out_kernel<<<(int)((size_t)BATCH * LEN / 4 / 256), 256, 0, stream>>>(x, noise, osd, out);
}

// Round 8
// 80.462 us; speedup vs baseline: 7.4895x; 1.0108x over previous
//
#include <hip/hip_runtime.h>

static constexpr int BATCH = 128;
static constexpr int LEN   = 131072;
static constexpr int T     = 4096;   // LEN / 32
static constexpr int DIM   = 32;
static constexpr int NP    = 16;

static constexpr int NCHUNK = 64;         // speculative chunks over T
static constexpr int SPC    = T / NCHUNK; // 64 steps per chunk
static constexpr int WARM   = 160;        // warm-up steps (0.9375^160 ~ 3e-5)

static constexpr int TT = 128;            // windows per scores-block

#define L2E   1.44269504088896340736f
#define L2E16 (1.44269504088896340736f / 16.0f)

typedef __attribute__((ext_vector_type(8))) short  short8;   // 8 bf16
typedef __attribute__((ext_vector_type(4))) float  f32x4;

__device__ __forceinline__ float fexp2(float x) {
#if __has_builtin(__builtin_amdgcn_exp2f)
  return __builtin_amdgcn_exp2f(x);
#else
  return exp2f(x);
#endif
}

__device__ __forceinline__ float frcp(float x) {
#if __has_builtin(__builtin_amdgcn_rcpf)
  return __builtin_amdgcn_rcpf(x);
#else
  return 1.0f / x;
#endif
}

template <int CTRL>
__device__ __forceinline__ float dppf(float v) {
  return __int_as_float(
      __builtin_amdgcn_update_dpp(0, __float_as_int(v), CTRL, 0xf, 0xf, true));
}

// Sum across each 16-lane group: butterfly over xor {1,2,7,15} via DPP.
__device__ __forceinline__ float sum16(float v) {
  v += dppf<0xB1>(v);
  v += dppf<0x4E>(v);
  v += dppf<0x141>(v);
  v += dppf<0x140>(v);
  return v;
}

// f32 -> bf16 round-to-nearest-even.
__device__ __forceinline__ short bf16c(float f) {
  unsigned u = __float_as_uint(f);
  unsigned r = u + 0x7fffu + ((u >> 16) & 1u);
  return (short)(r >> 16);
}

// One-shot prep: build bf16 MFMA fragments for conv_w / keys / bias in the
// exact per-lane layout scores_kernel consumes.
// Layout (shorts): [fs=fn*2+fk][lane][8] (4x1KB), kfrag [lane][8] (1KB),
// bias float2[lane] (512B). Total 5.6KB -> L1/L2-resident.
__global__ void __launch_bounds__(64) prep_kernel(
    const float* __restrict__ conv_w, const float* __restrict__ conv_b,
    const float* __restrict__ keys, short* __restrict__ frags) {
  int l = threadIdx.x;
  int ln15 = l & 15, kg = l >> 4;
#pragma unroll
  for (int fn = 0; fn < 2; ++fn)
#pragma unroll
    for (int fk = 0; fk < 2; ++fk) {
      const float* wp = conv_w + (fn * 16 + ln15) * 64 + fk * 32 + kg * 8;
      short* dst = frags + ((fn * 2 + fk) * 64 + l) * 8;
#pragma unroll
      for (int j = 0; j < 8; ++j) dst[j] = bf16c(wp[j]);
    }
  short* kd = frags + (256 + l) * 8;
#pragma unroll
  for (int j = 0; j < 8; ++j) kd[j] = bf16c(keys[(kg * 8 + j) * NP + ln15]);
  float* bp = (float*)(frags + 2560);
  bp[2 * l]     = conv_b[ln15];
  bp[2 * l + 1] = conv_b[16 + ln15];
}

// Stage 1 (MFMA, barrier-free): block = 256 thr (4 waves), one b, TT=128
// windows; each WAVE owns 32 windows and stages its OWN 2.1KB x-slice into a
// private LDS region -> no __syncthreads at all (same-wave DS ops are
// in-order). conv as GEMM via 16x16x32 bf16 MFMA (K=64 in 2 steps, N=32 in
// 2 tiles), relu+bias in D-layout, transpose through padded LDS (row stride
// 80B kills the R5 4-way bank conflicts, keeps b128 reads 16B-aligned),
// MFMA vs keys. Fragment layouts (m89-verified): A row=l&15,k=(l>>4)*8+j;
// B col=l&15, same k; C/D col=l&15, row=(l>>4)*4+reg.
// R7 bug fixed: staging must cover xw[0..1055]; main loop covers 0..1023,
// tail (lanes 0..31) now covers 1024..1055 (R7 left 1024..1039 stale).
__global__ void __launch_bounds__(256) scores_kernel(
    const float* __restrict__ x, const short* __restrict__ frags,
    _Float16* __restrict__ scoresh) {
  // per wave: xw[1088] (windows) + rl[16 rows x 40 shorts padded] = 1728 shorts
  __shared__ short lds[4][1728];

  int tid = threadIdx.x;
  int lane = tid & 63;
  int mt   = tid >> 6;     // wave id
  int blk = blockIdx.x;
  int b  = blk >> 5;
  int bt = blk & 31;
  int t0 = bt * TT;
  int T0w = t0 + mt * 32;              // this wave's first window
  const float* xb = x + (size_t)b * LEN;
  short* xw = lds[mt];                 // xw[i] = bf16(x[32*T0w - 63 + i]), i<1056
  short* rl = lds[mt] + 1088;          // relu(conv) [t][d], row stride 40

  // ---- per-wave staging: lane covers xw[16*lane-1 .. 16*lane+15].
  int gbase = 32 * T0w - 64 + 16 * lane;
  float f[17];
#pragma unroll
  for (int s = 0; s < 4; ++s) {
    int gi = gbase + 4 * s;
    float4 v = make_float4(0.f, 0.f, 0.f, 0.f);
    if (gi >= 0) v = *(const float4*)(xb + gi);   // 16B-aligned
    f[4 * s]     = v.x; f[4 * s + 1] = v.y;
    f[4 * s + 2] = v.z; f[4 * s + 3] = v.w;
  }
  f[16] = (gbase + 16 >= 0) ? xb[gbase + 16] : 0.f;

  short8 w0, w1;
#pragma unroll
  for (int j = 0; j < 8; ++j) { w0[j] = bf16c(f[j + 1]); w1[j] = bf16c(f[j + 9]); }
  *(short8*)(&xw[16 * lane])     = w0;
  *(short8*)(&xw[16 * lane + 8]) = w1;
  if (lane > 0) xw[16 * lane - 1] = bf16c(f[0]);
  if (lane < 32)                        // tail: xw[1024..1055] (global +961..+992)
    xw[1024 + lane] = bf16c(xb[32 * T0w + 961 + lane]);

  int ln15 = lane & 15;
  int kg   = lane >> 4;    // 0..3

  // Prebuilt fragments: 5x16B + 8B, coalesced, L2-hot.
  const short8* wf = (const short8*)frags;
  short8 bw00 = wf[0 * 64 + lane];
  short8 bw01 = wf[1 * 64 + lane];
  short8 bw10 = wf[2 * 64 + lane];
  short8 bw11 = wf[3 * 64 + lane];
  short8 bk   = wf[4 * 64 + lane];
  const float2* bp = (const float2*)(frags + 2560);
  float2 bias = bp[lane];

  _Float16* dstb = scoresh + (b & 3) * 16 + ln15;

#pragma unroll
  for (int st = 0; st < 2; ++st) {
    int tl = st * 16 + ln15;                     // window row within wave
    const short* ap = &xw[32 * tl];              // 16B-aligned (64B row stride)
    short8 a0 = *(const short8*)(ap + kg * 8);
    short8 a1 = *(const short8*)(ap + 32 + kg * 8);

    f32x4 acc0 = {0.f, 0.f, 0.f, 0.f};
    f32x4 acc1 = {0.f, 0.f, 0.f, 0.f};
    acc0 = __builtin_amdgcn_mfma_f32_16x16x32_bf16(a0, bw00, acc0, 0, 0, 0);
    acc0 = __builtin_amdgcn_mfma_f32_16x16x32_bf16(a1, bw01, acc0, 0, 0, 0);
    acc1 = __builtin_amdgcn_mfma_f32_16x16x32_bf16(a0, bw10, acc1, 0, 0, 0);
    acc1 = __builtin_amdgcn_mfma_f32_16x16x32_bf16(a1, bw11, acc1, 0, 0, 0);

    // relu(conv+bias) -> bf16 -> padded LDS [t][d] (transpose).
    // Row stride 40 shorts = 80B: kg*320B % 128B = {0,64} -> 2-way (free).
#pragma unroll
    for (int r = 0; r < 4; ++r) {
      int trow = kg * 4 + r;                     // D row = (l>>4)*4 + r
      rl[trow * 40 + ln15]      = bf16c(fmaxf(acc0[r] + bias.x, 0.f));
      rl[trow * 40 + 16 + ln15] = bf16c(fmaxf(acc1[r] + bias.y, 0.f));
    }
    // Same-wave DS ops are in-order: no barrier needed (reads see writes,
    // next st's writes can't pass this read - WAR safe).
    short8 a2 = *(const short8*)(&rl[ln15 * 40 + kg * 8]);  // 80B rows: aligned
    f32x4 acc2 = {0.f, 0.f, 0.f, 0.f};
    acc2 = __builtin_amdgcn_mfma_f32_16x16x32_bf16(a2, bk, acc2, 0, 0, 0);

    // D2: p = ln15, t = T0w + st*16 + kg*4 + r. clip*log2e -> f16.
#pragma unroll
    for (int r = 0; r < 4; ++r) {
      float s = fminf(fmaxf(acc2[r], 0.f), 6.f) * L2E;
      int t = T0w + st * 16 + kg * 4 + r;
      dstb[((size_t)(b >> 2) * T + t) * 64] = (_Float16)s;
    }
  }
}

// Stage 2: speculative-parallel softmax-scan, 16-deep register prefetch in
// named scalars (R4 8-deep left ~L3 latency exposed; 16 steps x ~60cyc covers
// ~1000cyc). Commit steps exploit group-uniform rc = 1/sum(e):
// o = rc*sum16(e*sh) -> the three sum16 butterflies run in parallel.
__global__ void __launch_bounds__(64) scan_kernel(
    const _Float16* __restrict__ scoresh, const float* __restrict__ avg0,
    const float* __restrict__ shapes, float2* __restrict__ osd) {
  int lane = threadIdx.x;
  int g = blockIdx.x & 31;   // batch-group (4 batches)
  int c = blockIdx.x >> 5;   // chunk
  int gid = g * 64 + lane;   // = b*16 + p
  int p = lane & 15;
  int bb = gid >> 4;
  float A = avg0[gid] * L2E;
  float sh0 = shapes[2 * p];
  float sh1 = shapes[2 * p + 1];
  int w = min(WARM, c * SPC);        // c=0 exact; w in {0,64,128,160} (%16==0)
  int tbeg = c * SPC - w;
  const _Float16* sp = scoresh + ((size_t)g * T + tbeg) * 64 + lane;

  float q0 = (float)sp[0 * 64],  q1 = (float)sp[1 * 64];
  float q2 = (float)sp[2 * 64],  q3 = (float)sp[3 * 64];
  float q4 = (float)sp[4 * 64],  q5 = (float)sp[5 * 64];
  float q6 = (float)sp[6 * 64],  q7 = (float)sp[7 * 64];
  float q8 = (float)sp[8 * 64],  q9 = (float)sp[9 * 64];
  float qa = (float)sp[10 * 64], qb = (float)sp[11 * 64];
  float qc = (float)sp[12 * 64], qd = (float)sp[13 * 64];
  float qe = (float)sp[14 * 64], qf = (float)sp[15 * 64];
  sp += 16 * 64;

#define WSTEP(Q)                                   \
  do {                                             \
    float e = fexp2(Q - A);                        \
    float r = sum16(e);                            \
    A = fmaf(e * L2E, frcp(r), A - L2E16);         \
    Q = (float)sp[0];                              \
    sp += 64;                                      \
  } while (0)

  for (int i = 0; i < w; i += 16) {
    WSTEP(q0); WSTEP(q1); WSTEP(q2); WSTEP(q3);
    WSTEP(q4); WSTEP(q5); WSTEP(q6); WSTEP(q7);
    WSTEP(q8); WSTEP(q9); WSTEP(qa); WSTEP(qb);
    WSTEP(qc); WSTEP(qd); WSTEP(qe); WSTEP(qf);
  }

  float2* od = osd + (size_t)bb * T + c * SPC;
#define CSTEP(Q, idx)                              \
  do {                                             \
    float e = fexp2(Q - A);                        \
    float r  = sum16(e);                           \
    float u0 = sum16(e * sh0);                     \
    float u1 = sum16(e * sh1);                     \
    float rc = frcp(r);                            \
    A = fmaf(e * L2E, rc, A - L2E16);              \
    if (p == 0) od[idx] = make_float2(u0 * rc, u1 * rc); \
    Q = (float)sp[0];                              \
    sp += 64;                                      \
  } while (0)

  for (int i = 0; i < SPC; i += 16) {              // overrun <= 2KB (padded)
    CSTEP(q0, i + 0);  CSTEP(q1, i + 1);  CSTEP(q2, i + 2);  CSTEP(q3, i + 3);
    CSTEP(q4, i + 4);  CSTEP(q5, i + 5);  CSTEP(q6, i + 6);  CSTEP(q7, i + 7);
    CSTEP(q8, i + 8);  CSTEP(q9, i + 9);  CSTEP(qa, i + 10); CSTEP(qb, i + 11);
    CSTEP(qc, i + 12); CSTEP(qd, i + 13); CSTEP(qe, i + 14); CSTEP(qf, i + 15);
  }
#undef WSTEP
#undef CSTEP
}

// Stage 3: memory-bound elementwise. out = relu(offset + noise*std - x).
// At ~97% of achievable HBM BW (201MB @ ~33us) - at floor.
__global__ void __launch_bounds__(256) out_kernel(
    const float* __restrict__ x, const float* __restrict__ noise,
    const float2* __restrict__ osd, float* __restrict__ out) {
  size_t gid = (size_t)blockIdx.x * 256 + threadIdx.x;
  size_t i4 = gid * 4;
  int b = (int)(i4 >> 17);          // / LEN
  int l = (int)(i4 & (LEN - 1));
  int t = l >> 5;                   // window index (quad never spans t)
  float2 os = osd[(size_t)b * T + t];
  float4 xv = *(const float4*)(x + i4);
  float4 nv = *(const float4*)(noise + i4);
  float4 o;
  o.x = fmaxf(fmaf(nv.x, os.y, os.x) - xv.x, 0.f);
  o.y = fmaxf(fmaf(nv.y, os.y, os.x) - xv.y, 0.f);
  o.z = fmaxf(fmaf(nv.z, os.y, os.x) - xv.z, 0.f);
  o.w = fmaxf(fmaf(nv.w, os.y, os.x) - xv.w, 0.f);
  *(float4*)(out + i4) = o;
}

extern "C" void kernel_launch(void* const* d_in, const int* in_sizes, int n_in,
                              void* d_out, int out_size, void* d_ws, size_t ws_size,
                              hipStream_t stream) {
  const float* x      = (const float*)d_in[0];
  const float* avg0   = (const float*)d_in[1];
  const float* noise  = (const float*)d_in[2];
  const float* conv_w = (const float*)d_in[3];
  const float* conv_b = (const float*)d_in[4];
  const float* keys   = (const float*)d_in[5];
  const float* shapes = (const float*)d_in[6];
  float* out = (float*)d_out;

  _Float16* scoresh = (_Float16*)d_ws;                               // 16.78 MB
  // +4KB pad absorbs the 16-deep prefetch overrun of the last chunk.
  char* p1 = (char*)d_ws + ((size_t)T * BATCH * NP * 2 + 4096);
  float2* osd = (float2*)p1;                                          // 4 MB
  short* frags = (short*)(p1 + (size_t)BATCH * T * 8);                // 5.6 KB

  prep_kernel<<<1, 64, 0, stream>>>(conv_w, conv_b, keys, frags);
  scores_kernel<<<BATCH * (T / TT), 256, 0, stream>>>(x, frags, scoresh);
  scan_kernel<<<32 * NCHUNK, 64, 0, stream>>>(scoresh, avg0, shapes, osd);
  out_kernel<<<(int)((size_t)BATCH * LEN / 4 / 256), 256, 0, stream>>>(x, noise, osd, out);
}